// Round 10
// baseline (7348.648 us; speedup 1.0000x reference)
//
#include <hip/hip_runtime.h>
#include <hip/hip_bf16.h>

#define B_ 64
#define K_ 16
#define N_ 4096
#define C_ 384
#define M_ 4096
#define EPS_ 1e-8f

#define SEGROWS_ 128
#define MAXSEG_  32          // per (b,k): ceil(4096/128)
#define MAXDESC_ 48          // per b: sum_k ceil(cnt_k/128) < 48

#define TROWS_  16           // rows per LDS stage in sim (24 KB)
#define NSTAGE_ 16           // stages per block (256 rows)

// async global->LDS, 16B per lane, wave-uniform LDS base (+lane*16 in HW)
#define GLDS(gp, lp) __builtin_amdgcn_global_load_lds( \
    (const __attribute__((address_space(1))) unsigned int*)(gp), \
    (__attribute__((address_space(3))) unsigned int*)(lp), 16, 0, 0)

// ---------------------------------------------------------------------------
// init: copy input prototypes into ws and compute their norms
// ---------------------------------------------------------------------------
__global__ __launch_bounds__(384) void init_proto_kernel(
    const float* __restrict__ pin, float* __restrict__ proto,
    float* __restrict__ pnorm)
{
    const int bk = blockIdx.x;
    const int c  = threadIdx.x;            // 384 threads, c == channel
    float v = pin[(size_t)bk * C_ + c];
    proto[(size_t)bk * C_ + c] = v;
    float sq = v * v;
    #pragma unroll
    for (int m = 1; m <= 32; m <<= 1) sq += __shfl_xor(sq, m, 64);
    __shared__ float red[6];
    const int w = c >> 6, lane = c & 63;
    if (lane == 0) red[w] = sq;
    __syncthreads();
    if (c == 0) {
        float t = red[0] + red[1] + red[2] + red[3] + red[4] + red[5];
        pnorm[bk] = sqrtf(t);
    }
}

// ---------------------------------------------------------------------------
// sim: sim[b,k,n] = dot(proto[b,k],feats_row[n]) / max(pnorm*fnorm, EPS)
// LDS-staged pipeline (global_load_lds, linear dest). STRIDED chunk layout:
// lane cc reads 16B-chunks {cc+16i, i=0..5} of the 96-chunk row -> consecutive
// lanes hit consecutive bank-quads (2-way = conflict-free). Proto fragments
// use the same chunk layout so the dot products stay element-aligned.
// NM: 0 = compute row norm + store to fnorm; 1 = load fnorm; 2 = compute only.
// ---------------------------------------------------------------------------
template <int NM>
__global__ __launch_bounds__(256) void sim_kernel(
    const float* __restrict__ proto,   // [B,K,C]
    const float* __restrict__ pnorm,   // [B,K]
    const float* __restrict__ feats,   // rows [nrows, C], per-b stride bstride
    float* __restrict__ fnorm,         // [B,nrows] (store NM=0 / load NM=1)
    float* __restrict__ simout,        // [B,K,nrows]
    int nrows, long long bstride)
{
    const int b    = blockIdx.y;
    const int tile = blockIdx.x;           // 256 rows per block
    const int tid  = threadIdx.x;
    const int wave = tid >> 6;
    const int lane = tid & 63;
    const int kg   = lane & 3;
    const int cc   = lane >> 2;
    const int p    = cc & 1;
    const int q    = (cc >> 1) & 1;

    __shared__ float lbuf[2][TROWS_ * C_];     // 2 x 24 KB

    // writer-lane k mapping and its prototype norm
    const int k_w = (lane & 3) * 4 + 2 * ((lane >> 3) & 1) + ((lane >> 2) & 1);
    const float pn_w = pnorm[b * K_ + (k_w & 15)];

    // prototype fragments in registers: 4 k's x 6 strided 16B chunks
    float4 pr[4][6];
    const float* pb = proto + (size_t)b * K_ * C_;
    #pragma unroll
    for (int j = 0; j < 4; ++j) {
        const float* prow = pb + (size_t)(kg * 4 + j) * C_;
        #pragma unroll
        for (int i = 0; i < 6; ++i)
            pr[j][i] = *(const float4*)(prow + (cc + 16 * i) * 4);
    }

    const float* fb = feats + (size_t)b * bstride;
    const int nbase0 = tile * (TROWS_ * NSTAGE_);

    // stage st -> buffer s: linear 24 KB copy, 6 calls x 4 KB
    const int loff = wave * 256 + lane * 4;    // float offset of this lane's 16B
    #define STAGE_(s, st) do {                                              \
        const float* g_ = fb + (size_t)(nbase0 + (st) * TROWS_) * C_ + loff;\
        float* l_ = &lbuf[s][wave * 256];                                   \
        _Pragma("unroll")                                                   \
        for (int i_ = 0; i_ < 6; ++i_)                                      \
            GLDS(g_ + i_ * 1024, l_ + i_ * 1024);                           \
    } while (0)

    STAGE_(0, 0);
    __syncthreads();

    for (int st = 0; st < NSTAGE_; ++st) {
        if (st + 1 < NSTAGE_) STAGE_((st + 1) & 1, st + 1);

        const float* lb = &lbuf[st & 1][0];
        #pragma unroll
        for (int r = 0; r < 4; ++r) {
            const int row = wave * 4 + r;
            const int n = nbase0 + st * TROWS_ + row;
            const float* frow = lb + row * C_;
            float4 f[6];
            #pragma unroll
            for (int i = 0; i < 6; ++i)
                f[i] = *(const float4*)(frow + (cc + 16 * i) * 4);

            float s0 = 0.f, s1 = 0.f, s2 = 0.f, s3 = 0.f, nsq = 0.f;
            #pragma unroll
            for (int i = 0; i < 6; ++i) {
                if (NM != 1)
                    nsq += f[i].x * f[i].x + f[i].y * f[i].y
                         + f[i].z * f[i].z + f[i].w * f[i].w;
                s0 += f[i].x * pr[0][i].x + f[i].y * pr[0][i].y
                    + f[i].z * pr[0][i].z + f[i].w * pr[0][i].w;
                s1 += f[i].x * pr[1][i].x + f[i].y * pr[1][i].y
                    + f[i].z * pr[1][i].z + f[i].w * pr[1][i].w;
                s2 += f[i].x * pr[2][i].x + f[i].y * pr[2][i].y
                    + f[i].z * pr[2][i].z + f[i].w * pr[2][i].w;
                s3 += f[i].x * pr[3][i].x + f[i].y * pr[3][i].y
                    + f[i].z * pr[3][i].z + f[i].w * pr[3][i].w;
            }
            // fold A: merge {s0,s1} across cc bit0 (lane bit2)
            float sendA = p ? s0 : s1;
            float recvA = __shfl_xor(sendA, 4, 64);
            float a = (p ? s1 : s0) + recvA;
            // fold B: merge {s2,s3}
            float sendB = p ? s2 : s3;
            float recvB = __shfl_xor(sendB, 4, 64);
            float bb = (p ? s3 : s2) + recvB;
            // fold C: merge {a,b} across cc bit1 (lane bit3)
            float sendC = q ? a : bb;
            float recvC = __shfl_xor(sendC, 8, 64);
            float d = (q ? bb : a) + recvC;
            d += __shfl_xor(d, 16, 64);
            d += __shfl_xor(d, 32, 64);

            float fn;
            if (NM == 1) {
                fn = fnorm[(size_t)b * nrows + n];
            } else {
                #pragma unroll
                for (int m = 4; m <= 32; m <<= 1) nsq += __shfl_xor(nsq, m, 64);
                fn = sqrtf(nsq);
                if (NM == 0 && lane == 0) fnorm[(size_t)b * nrows + n] = fn;
            }
            if (lane < 16) {
                const float denom = fmaxf(pn_w * fn, EPS_);
                simout[((size_t)b * K_ + k_w) * (size_t)nrows + n] = d / denom;
            }
        }
        __syncthreads();
    }
    #undef STAGE_
}

// ---------------------------------------------------------------------------
// stats: per (b,k): density->tau->inv (from prev mask), rowmax, rowsum(exp)
// ---------------------------------------------------------------------------
__global__ __launch_bounds__(256) void stats_kernel(
    const float* __restrict__ sim,     // [B,K,N]
    const int* __restrict__ kmaxp,     // [B,N] previous-iteration assignment
    float* __restrict__ inv, float* __restrict__ rowmax,
    float* __restrict__ rowsum, int iter0)
{
    const int bk = blockIdx.x;
    const int b = bk >> 4, k = bk & 15;
    const int t = threadIdx.x;
    const float* row = sim + (size_t)bk * N_;
    const int*   km  = kmaxp + (size_t)b * N_;

    float4 v[4];
    float mx = -3.0e38f, ms = 0.f;
    int mc = 0;
    #pragma unroll
    for (int i = 0; i < 4; ++i) {
        v[i] = ((const float4*)row)[i * 256 + t];
        mx = fmaxf(mx, fmaxf(fmaxf(v[i].x, v[i].y), fmaxf(v[i].z, v[i].w)));
    }
    if (!iter0) {
        #pragma unroll
        for (int i = 0; i < 4; ++i) {
            const int4 kk = ((const int4*)km)[i * 256 + t];
            if (kk.x == k) { ms += v[i].x; mc++; }
            if (kk.y == k) { ms += v[i].y; mc++; }
            if (kk.z == k) { ms += v[i].z; mc++; }
            if (kk.w == k) { ms += v[i].w; mc++; }
        }
    }
    __shared__ float smx[4], sms[4];
    __shared__ int   smc[4];
    #pragma unroll
    for (int m = 1; m <= 32; m <<= 1) {
        mx = fmaxf(mx, __shfl_xor(mx, m, 64));
        ms += __shfl_xor(ms, m, 64);
        mc += __shfl_xor(mc, m, 64);
    }
    const int w = t >> 6, lane = t & 63;
    if (lane == 0) { smx[w] = mx; sms[w] = ms; smc[w] = mc; }
    __syncthreads();
    mx = fmaxf(fmaxf(smx[0], smx[1]), fmaxf(smx[2], smx[3]));
    ms = sms[0] + sms[1] + sms[2] + sms[3];
    mc = smc[0] + smc[1] + smc[2] + smc[3];

    float invv;
    if (iter0) {
        invv = 100.f;                     // 1/(temp*tau0) = 1/(0.1*0.1)
    } else {
        const float d   = (mc >= 1) ? (1.f - ms / (float)mc) : 1.f;
        const float tau = fmaxf(d, 1e-10f);
        invv = 1.f / (0.1f * tau);
    }
    float es = 0.f;
    #pragma unroll
    for (int i = 0; i < 4; ++i) {
        es += expf((v[i].x - mx) * invv) + expf((v[i].y - mx) * invv)
            + expf((v[i].z - mx) * invv) + expf((v[i].w - mx) * invv);
    }
    #pragma unroll
    for (int m = 1; m <= 32; m <<= 1) es += __shfl_xor(es, m, 64);
    __syncthreads();
    if (lane == 0) sms[w] = es;
    __syncthreads();
    if (t == 0) {
        rowmax[bk] = mx;
        rowsum[bk] = sms[0] + sms[1] + sms[2] + sms[3];
        inv[bk]    = invv;
    }
}

// ---------------------------------------------------------------------------
// argmax over k of softmax weight; full-machine grid (16,64). Emits winner
// index + winning weight to global for the (light) build kernel.
// ---------------------------------------------------------------------------
__global__ __launch_bounds__(256) void argmax_kernel(
    const float* __restrict__ sim, const float* __restrict__ rowmax,
    const float* __restrict__ rowsum, const float* __restrict__ inv,
    int* __restrict__ kmaxo, float* __restrict__ wselo)
{
    const int b = blockIdx.y;
    const int n = blockIdx.x * 256 + threadIdx.x;
    float best = -1.f;
    int bi = 0;
    #pragma unroll
    for (int k = 0; k < K_; ++k) {
        const float s = sim[((size_t)b * K_ + k) * N_ + n];
        const float w = expf((s - rowmax[b * K_ + k]) * inv[b * K_ + k])
                        / rowsum[b * K_ + k];
        if (w > best) { best = w; bi = k; }   // strict > keeps first (jnp tie rule)
    }
    kmaxo[(size_t)b * N_ + n] = bi;
    wselo[(size_t)b * N_ + n] = best;
}

// ---------------------------------------------------------------------------
// build per-(b,k) contiguous index lists (n ascending, deterministic via
// ballot/popc) + segment descriptors. Also: zeroes the per-(b,k) completion
// counters for this iteration's update, and writes proto=0/pnorm=0 for empty
// clusters (no segment block will produce them).
// ---------------------------------------------------------------------------
__global__ __launch_bounds__(256) void build_lists_kernel(
    const int* __restrict__ kmax, const float* __restrict__ wsel,
    int* __restrict__ listn, float* __restrict__ listw,
    int* __restrict__ cnt, int4* __restrict__ desc, int* __restrict__ segcnt,
    int* __restrict__ ctr, float* __restrict__ proto, float* __restrict__ pnorm)
{
    const int b = blockIdx.x;
    const int t = threadIdx.x;
    const int wave = t >> 6, lane = t & 63;
    const int* km = kmax + (size_t)b * N_;
    const float* wv = wsel + (size_t)b * N_;
    const unsigned long long lt = (1ull << lane) - 1ull;

    __shared__ int scnt[4][16];

    if (t < K_) ctr[b * K_ + t] = 0;       // reset completion counters

    int c[16];
    #pragma unroll
    for (int k = 0; k < 16; ++k) c[k] = 0;
    const int qbase = wave * 1024;
    for (int base = 0; base < 1024; base += 64) {
        const int kk = km[qbase + base + lane];
        #pragma unroll
        for (int k = 0; k < 16; ++k)
            c[k] += __popcll(__ballot(kk == k));
    }
    if (lane == 0) {
        #pragma unroll
        for (int k = 0; k < 16; ++k) scnt[wave][k] = c[k];
    }
    __syncthreads();

    int tot[16], koff[16];
    int acc = 0;
    #pragma unroll
    for (int k = 0; k < 16; ++k) {
        tot[k] = scnt[0][k] + scnt[1][k] + scnt[2][k] + scnt[3][k];
        koff[k] = acc; acc += tot[k];
    }
    int run[16];
    #pragma unroll
    for (int k = 0; k < 16; ++k) {
        run[k] = koff[k]
               + (wave > 0 ? scnt[0][k] : 0)
               + (wave > 1 ? scnt[1][k] : 0)
               + (wave > 2 ? scnt[2][k] : 0);
    }

    // empty clusters: write proto = 0, pnorm = 0 (no segment will exist)
    #pragma unroll
    for (int k = 0; k < 16; ++k) {
        if (tot[k] == 0) {
            float* pd = proto + ((size_t)b * K_ + k) * C_;
            for (int c2 = t; c2 < C_; c2 += 256) pd[c2] = 0.f;
            if (t == 0) pnorm[b * K_ + k] = 0.f;
        }
    }

    for (int base = 0; base < 1024; base += 64) {
        const int n = qbase + base + lane;
        const int kk = km[n];
        const float w = wv[n];
        #pragma unroll
        for (int k = 0; k < 16; ++k) {
            const unsigned long long m = __ballot(kk == k);
            if (kk == k) {
                const int pos = run[k] + __popcll(m & lt);
                listn[(size_t)b * N_ + pos] = n;
                listw[(size_t)b * N_ + pos] = w;
            }
            run[k] += __popcll(m);
        }
    }

    if (t == 0) {
        int j = 0;
        for (int k = 0; k < 16; ++k) {
            cnt[b * K_ + k] = tot[k];
            for (int s = 0; s < tot[k]; s += SEGROWS_) {
                desc[b * MAXDESC_ + j] =
                    make_int4(k, koff[k] + s, min(SEGROWS_, tot[k] - s),
                              s / SEGROWS_);
                ++j;
            }
        }
        segcnt[b] = j;
    }
}

// ---------------------------------------------------------------------------
// prototype update, fused: one block per 128-row segment of a single (b,k).
// 4 FMA per float4, 2-deep software prefetch. After writing its partial, the
// block that completes the per-(b,k) counter reduces all segments IN FIXED
// ASCENDING ORDER (bit-identical to the old separate reduce kernel), writes
// proto + pnorm, and on the last iteration also writes the final output.
// ---------------------------------------------------------------------------
__global__ __launch_bounds__(384) void partial_update_kernel(
    const int* __restrict__ listn, const float* __restrict__ listw,
    const int* __restrict__ segcnt, const int4* __restrict__ desc,
    const int* __restrict__ cnt, int* __restrict__ ctr,
    const float* __restrict__ feats,
    float* __restrict__ partial,       // [B*K, MAXSEG, C]
    float* __restrict__ proto, float* __restrict__ pnorm,
    float* __restrict__ outp)          // != nullptr on last iteration
{
    const int b = blockIdx.y;
    const int j = blockIdx.x;
    if (j >= segcnt[b]) return;
    const int4 dd = desc[b * MAXDESC_ + j];
    const int k = dd.x, start = dd.y, rows = dd.z, seg = dd.w;
    const int t = threadIdx.x;
    const int rg = t / 96, ci = t % 96;
    const int bk = b * K_ + k;

    __shared__ int   sn[SEGROWS_];
    __shared__ float sw[SEGROWS_];
    if (t < SEGROWS_) {
        const int ok = t < rows;
        sn[t] = ok ? listn[(size_t)b * N_ + start + t] : 0;
        sw[t] = ok ? listw[(size_t)b * N_ + start + t] : 0.f;
    }
    __syncthreads();

    const float4* fb = (const float4*)(feats + (size_t)b * N_ * C_);
    float4 acc = make_float4(0.f, 0.f, 0.f, 0.f);
    if (rg < rows) {
        const int last = rows - 1;
        float  w0 = sw[rg];
        float4 f0 = fb[(size_t)sn[rg] * 96 + ci];
        const int i1 = (rg + 4 <= last) ? rg + 4 : last;
        float  w1 = sw[i1];
        float4 f1 = fb[(size_t)sn[i1] * 96 + ci];
        for (int i = rg; i < rows; i += 4) {
            const int i2 = (i + 8 <= last) ? i + 8 : last;   // clamped prefetch
            const float  w2 = sw[i2];
            const float4 f2 = fb[(size_t)sn[i2] * 96 + ci];
            acc.x += w0 * f0.x; acc.y += w0 * f0.y;
            acc.z += w0 * f0.z; acc.w += w0 * f0.w;
            w0 = w1; f0 = f1;
            w1 = w2; f1 = f2;
        }
    }
    __shared__ float4 sacc[3][96];
    if (rg > 0) sacc[rg - 1][ci] = acc;
    __syncthreads();
    if (rg == 0) {
        acc.x += sacc[0][ci].x + sacc[1][ci].x + sacc[2][ci].x;
        acc.y += sacc[0][ci].y + sacc[1][ci].y + sacc[2][ci].y;
        acc.z += sacc[0][ci].z + sacc[1][ci].z + sacc[2][ci].z;
        acc.w += sacc[0][ci].w + sacc[1][ci].w + sacc[2][ci].w;
        ((float4*)partial)[((size_t)bk * MAXSEG_ + seg) * 96 + ci] = acc;
    }
    __syncthreads();

    // completion counting; last-arriving block reduces (fixed seg order)
    const int nseg = (cnt[bk] + SEGROWS_ - 1) / SEGROWS_;
    __shared__ int isred;
    __threadfence();
    if (t == 0) isred = (atomicAdd(&ctr[bk], 1) == nseg - 1) ? 1 : 0;
    __syncthreads();
    if (!isred) return;
    __threadfence();

    const int c = t;                       // 384 threads = channels
    float racc = 0.f;
    for (int s = 0; s < nseg; ++s)
        racc += partial[((size_t)bk * MAXSEG_ + s) * C_ + c];
    proto[(size_t)bk * C_ + c] = racc;
    if (outp) outp[(size_t)bk * C_ + c] = racc;

    float sq = racc * racc;
    #pragma unroll
    for (int m = 1; m <= 32; m <<= 1) sq += __shfl_xor(sq, m, 64);
    __shared__ float red[6];
    const int w = c >> 6, lane = c & 63;
    if (lane == 0) red[w] = sq;
    __syncthreads();
    if (c == 0) {
        float tt = red[0] + red[1] + red[2] + red[3] + red[4] + red[5];
        pnorm[bk] = sqrtf(tt);
    }
}

// ---------------------------------------------------------------------------
extern "C" void kernel_launch(void* const* d_in, const int* in_sizes, int n_in,
                              void* d_out, int out_size, void* d_ws, size_t ws_size,
                              hipStream_t stream) {
    const float* pin   = (const float*)d_in[0];   // [B,K,C]
    const float* feats = (const float*)d_in[1];   // [B,N,C]
    const float* forg  = (const float*)d_in[2];   // [M,C]
    float* out = (float*)d_out;

    // workspace carve (floats; every block is a multiple of 4 elems = 16B)
    float* ws = (float*)d_ws;
    size_t o = 0;
    float* proto   = ws + o; o += (size_t)B_ * K_ * C_;            // 393216
    float* pnorm   = ws + o; o += 1024;
    float* inv     = ws + o; o += 1024;
    float* rowmax  = ws + o; o += 1024;
    float* rowsum  = ws + o; o += 1024;
    float* fnorm   = ws + o; o += (size_t)B_ * N_;                 // 262144
    float* wsel    = ws + o; o += (size_t)B_ * N_;                 // 262144
    float* listw   = ws + o; o += (size_t)B_ * N_;                 // 262144
    float* sim     = ws + o; o += (size_t)B_ * K_ * N_;            // 4194304
    float* partial = ws + o; o += (size_t)B_ * K_ * MAXSEG_ * C_;  // 12582912
    int*  kmax   = (int*)(ws + o); o += (size_t)B_ * N_;
    int*  listn  = (int*)(ws + o); o += (size_t)B_ * N_;
    int*  cnt    = (int*)(ws + o); o += 1024;
    int*  segcnt = (int*)(ws + o); o += 1024;
    int*  ctr    = (int*)(ws + o); o += 1024;
    int4* desc   = (int4*)(ws + o); o += (size_t)B_ * MAXDESC_ * 4;

    init_proto_kernel<<<B_ * K_, 384, 0, stream>>>(pin, proto, pnorm);
    // pass 1: compute + store row norms
    sim_kernel<0><<<dim3(N_ / 256, B_), 256, 0, stream>>>(
        proto, pnorm, feats, fnorm, sim, N_, (long long)N_ * C_);

    for (int it = 0; it < 5; ++it) {
        stats_kernel<<<B_ * K_, 256, 0, stream>>>(
            sim, kmax, inv, rowmax, rowsum, it == 0 ? 1 : 0);
        argmax_kernel<<<dim3(N_ / 256, B_), 256, 0, stream>>>(
            sim, rowmax, rowsum, inv, kmax, wsel);
        build_lists_kernel<<<B_, 256, 0, stream>>>(
            kmax, wsel, listn, listw, cnt, desc, segcnt, ctr, proto, pnorm);
        partial_update_kernel<<<dim3(MAXDESC_, B_), 384, 0, stream>>>(
            listn, listw, segcnt, desc, cnt, ctr, feats, partial,
            proto, pnorm, it == 4 ? out : nullptr);
        if (it < 4) {
            sim_kernel<1><<<dim3(N_ / 256, B_), 256, 0, stream>>>(
                proto, pnorm, feats, fnorm, sim, N_, (long long)N_ * C_);
        }
    }

    // final: sim against feats_org -> d_out sim region (norms computed in-pass)
    sim_kernel<2><<<dim3(M_ / 256, B_), 256, 0, stream>>>(
        proto, pnorm, forg, fnorm, out + (size_t)B_ * K_ * C_, M_, 0LL);
}

// Round 11
// 1435.711 us; speedup vs baseline: 5.1185x; 5.1185x over previous
//
#include <hip/hip_runtime.h>
#include <hip/hip_bf16.h>

#define B_ 64
#define K_ 16
#define N_ 4096
#define C_ 384
#define M_ 4096
#define EPS_ 1e-8f

#define SEGROWS_ 128
#define MAXSEG_  32          // per (b,k): ceil(4096/128)
#define MAXDESC_ 48          // per b: sum_k ceil(cnt_k/128) < 48

#define TROWS_  16           // rows per LDS stage in sim (24 KB)
#define NSTAGE_ 16           // stages per block (256 rows)

// async global->LDS, 16B per lane, wave-uniform LDS base (+lane*16 in HW)
#define GLDS(gp, lp) __builtin_amdgcn_global_load_lds( \
    (const __attribute__((address_space(1))) unsigned int*)(gp), \
    (__attribute__((address_space(3))) unsigned int*)(lp), 16, 0, 0)

// ---------------------------------------------------------------------------
// init: copy input prototypes into ws and compute their norms
// ---------------------------------------------------------------------------
__global__ __launch_bounds__(384) void init_proto_kernel(
    const float* __restrict__ pin, float* __restrict__ proto,
    float* __restrict__ pnorm)
{
    const int bk = blockIdx.x;
    const int c  = threadIdx.x;            // 384 threads, c == channel
    float v = pin[(size_t)bk * C_ + c];
    proto[(size_t)bk * C_ + c] = v;
    float sq = v * v;
    #pragma unroll
    for (int m = 1; m <= 32; m <<= 1) sq += __shfl_xor(sq, m, 64);
    __shared__ float red[6];
    const int w = c >> 6, lane = c & 63;
    if (lane == 0) red[w] = sq;
    __syncthreads();
    if (c == 0) {
        float t = red[0] + red[1] + red[2] + red[3] + red[4] + red[5];
        pnorm[bk] = sqrtf(t);
    }
}

// ---------------------------------------------------------------------------
// sim: sim[b,k,n] = dot(proto[b,k],feats_row[n]) / max(pnorm*fnorm, EPS)
// LDS-staged pipeline (global_load_lds, linear dest). STRIDED chunk layout:
// lane cc reads 16B-chunks {cc+16i, i=0..5} of the 96-chunk row -> consecutive
// lanes hit consecutive bank-quads (2-way = conflict-free). Proto fragments
// use the same chunk layout so the dot products stay element-aligned.
// NM: 0 = compute row norm + store to fnorm; 1 = load fnorm; 2 = compute only.
// ---------------------------------------------------------------------------
template <int NM>
__global__ __launch_bounds__(256) void sim_kernel(
    const float* __restrict__ proto,   // [B,K,C]
    const float* __restrict__ pnorm,   // [B,K]
    const float* __restrict__ feats,   // rows [nrows, C], per-b stride bstride
    float* __restrict__ fnorm,         // [B,nrows] (store NM=0 / load NM=1)
    float* __restrict__ simout,        // [B,K,nrows]
    int nrows, long long bstride)
{
    const int b    = blockIdx.y;
    const int tile = blockIdx.x;           // 256 rows per block
    const int tid  = threadIdx.x;
    const int wave = tid >> 6;
    const int lane = tid & 63;
    const int kg   = lane & 3;
    const int cc   = lane >> 2;
    const int p    = cc & 1;
    const int q    = (cc >> 1) & 1;

    __shared__ float lbuf[2][TROWS_ * C_];     // 2 x 24 KB

    // writer-lane k mapping and its prototype norm
    const int k_w = (lane & 3) * 4 + 2 * ((lane >> 3) & 1) + ((lane >> 2) & 1);
    const float pn_w = pnorm[b * K_ + (k_w & 15)];

    // prototype fragments in registers: 4 k's x 6 strided 16B chunks
    float4 pr[4][6];
    const float* pb = proto + (size_t)b * K_ * C_;
    #pragma unroll
    for (int j = 0; j < 4; ++j) {
        const float* prow = pb + (size_t)(kg * 4 + j) * C_;
        #pragma unroll
        for (int i = 0; i < 6; ++i)
            pr[j][i] = *(const float4*)(prow + (cc + 16 * i) * 4);
    }

    const float* fb = feats + (size_t)b * bstride;
    const int nbase0 = tile * (TROWS_ * NSTAGE_);

    // stage st -> buffer s: linear 24 KB copy, 6 calls x 4 KB
    const int loff = wave * 256 + lane * 4;    // float offset of this lane's 16B
    #define STAGE_(s, st) do {                                              \
        const float* g_ = fb + (size_t)(nbase0 + (st) * TROWS_) * C_ + loff;\
        float* l_ = &lbuf[s][wave * 256];                                   \
        _Pragma("unroll")                                                   \
        for (int i_ = 0; i_ < 6; ++i_)                                      \
            GLDS(g_ + i_ * 1024, l_ + i_ * 1024);                           \
    } while (0)

    STAGE_(0, 0);
    __syncthreads();

    for (int st = 0; st < NSTAGE_; ++st) {
        if (st + 1 < NSTAGE_) STAGE_((st + 1) & 1, st + 1);

        const float* lb = &lbuf[st & 1][0];
        #pragma unroll
        for (int r = 0; r < 4; ++r) {
            const int row = wave * 4 + r;
            const int n = nbase0 + st * TROWS_ + row;
            const float* frow = lb + row * C_;
            float4 f[6];
            #pragma unroll
            for (int i = 0; i < 6; ++i)
                f[i] = *(const float4*)(frow + (cc + 16 * i) * 4);

            float s0 = 0.f, s1 = 0.f, s2 = 0.f, s3 = 0.f, nsq = 0.f;
            #pragma unroll
            for (int i = 0; i < 6; ++i) {
                if (NM != 1)
                    nsq += f[i].x * f[i].x + f[i].y * f[i].y
                         + f[i].z * f[i].z + f[i].w * f[i].w;
                s0 += f[i].x * pr[0][i].x + f[i].y * pr[0][i].y
                    + f[i].z * pr[0][i].z + f[i].w * pr[0][i].w;
                s1 += f[i].x * pr[1][i].x + f[i].y * pr[1][i].y
                    + f[i].z * pr[1][i].z + f[i].w * pr[1][i].w;
                s2 += f[i].x * pr[2][i].x + f[i].y * pr[2][i].y
                    + f[i].z * pr[2][i].z + f[i].w * pr[2][i].w;
                s3 += f[i].x * pr[3][i].x + f[i].y * pr[3][i].y
                    + f[i].z * pr[3][i].z + f[i].w * pr[3][i].w;
            }
            // fold A: merge {s0,s1} across cc bit0 (lane bit2)
            float sendA = p ? s0 : s1;
            float recvA = __shfl_xor(sendA, 4, 64);
            float a = (p ? s1 : s0) + recvA;
            // fold B: merge {s2,s3}
            float sendB = p ? s2 : s3;
            float recvB = __shfl_xor(sendB, 4, 64);
            float bb = (p ? s3 : s2) + recvB;
            // fold C: merge {a,b} across cc bit1 (lane bit3)
            float sendC = q ? a : bb;
            float recvC = __shfl_xor(sendC, 8, 64);
            float d = (q ? bb : a) + recvC;
            d += __shfl_xor(d, 16, 64);
            d += __shfl_xor(d, 32, 64);

            float fn;
            if (NM == 1) {
                fn = fnorm[(size_t)b * nrows + n];
            } else {
                #pragma unroll
                for (int m = 4; m <= 32; m <<= 1) nsq += __shfl_xor(nsq, m, 64);
                fn = sqrtf(nsq);
                if (NM == 0 && lane == 0) fnorm[(size_t)b * nrows + n] = fn;
            }
            if (lane < 16) {
                const float denom = fmaxf(pn_w * fn, EPS_);
                simout[((size_t)b * K_ + k_w) * (size_t)nrows + n] = d / denom;
            }
        }
        __syncthreads();
    }
    #undef STAGE_
}

// ---------------------------------------------------------------------------
// stats: per (b,k): density->tau->inv (from prev mask), rowmax, rowsum(exp)
// ---------------------------------------------------------------------------
__global__ __launch_bounds__(256) void stats_kernel(
    const float* __restrict__ sim,     // [B,K,N]
    const int* __restrict__ kmaxp,     // [B,N] previous-iteration assignment
    float* __restrict__ inv, float* __restrict__ rowmax,
    float* __restrict__ rowsum, int iter0)
{
    const int bk = blockIdx.x;
    const int b = bk >> 4, k = bk & 15;
    const int t = threadIdx.x;
    const float* row = sim + (size_t)bk * N_;
    const int*   km  = kmaxp + (size_t)b * N_;

    float4 v[4];
    float mx = -3.0e38f, ms = 0.f;
    int mc = 0;
    #pragma unroll
    for (int i = 0; i < 4; ++i) {
        v[i] = ((const float4*)row)[i * 256 + t];
        mx = fmaxf(mx, fmaxf(fmaxf(v[i].x, v[i].y), fmaxf(v[i].z, v[i].w)));
    }
    if (!iter0) {
        #pragma unroll
        for (int i = 0; i < 4; ++i) {
            const int4 kk = ((const int4*)km)[i * 256 + t];
            if (kk.x == k) { ms += v[i].x; mc++; }
            if (kk.y == k) { ms += v[i].y; mc++; }
            if (kk.z == k) { ms += v[i].z; mc++; }
            if (kk.w == k) { ms += v[i].w; mc++; }
        }
    }
    __shared__ float smx[4], sms[4];
    __shared__ int   smc[4];
    #pragma unroll
    for (int m = 1; m <= 32; m <<= 1) {
        mx = fmaxf(mx, __shfl_xor(mx, m, 64));
        ms += __shfl_xor(ms, m, 64);
        mc += __shfl_xor(mc, m, 64);
    }
    const int w = t >> 6, lane = t & 63;
    if (lane == 0) { smx[w] = mx; sms[w] = ms; smc[w] = mc; }
    __syncthreads();
    mx = fmaxf(fmaxf(smx[0], smx[1]), fmaxf(smx[2], smx[3]));
    ms = sms[0] + sms[1] + sms[2] + sms[3];
    mc = smc[0] + smc[1] + smc[2] + smc[3];

    float invv;
    if (iter0) {
        invv = 100.f;                     // 1/(temp*tau0) = 1/(0.1*0.1)
    } else {
        const float d   = (mc >= 1) ? (1.f - ms / (float)mc) : 1.f;
        const float tau = fmaxf(d, 1e-10f);
        invv = 1.f / (0.1f * tau);
    }
    float es = 0.f;
    #pragma unroll
    for (int i = 0; i < 4; ++i) {
        es += expf((v[i].x - mx) * invv) + expf((v[i].y - mx) * invv)
            + expf((v[i].z - mx) * invv) + expf((v[i].w - mx) * invv);
    }
    #pragma unroll
    for (int m = 1; m <= 32; m <<= 1) es += __shfl_xor(es, m, 64);
    __syncthreads();
    if (lane == 0) sms[w] = es;
    __syncthreads();
    if (t == 0) {
        rowmax[bk] = mx;
        rowsum[bk] = sms[0] + sms[1] + sms[2] + sms[3];
        inv[bk]    = invv;
    }
}

// ---------------------------------------------------------------------------
// argmax over k of softmax weight; full-machine grid (16,64). Emits winner
// index + winning weight to global for the (light) build kernel.
// ---------------------------------------------------------------------------
__global__ __launch_bounds__(256) void argmax_kernel(
    const float* __restrict__ sim, const float* __restrict__ rowmax,
    const float* __restrict__ rowsum, const float* __restrict__ inv,
    int* __restrict__ kmaxo, float* __restrict__ wselo)
{
    const int b = blockIdx.y;
    const int n = blockIdx.x * 256 + threadIdx.x;
    float best = -1.f;
    int bi = 0;
    #pragma unroll
    for (int k = 0; k < K_; ++k) {
        const float s = sim[((size_t)b * K_ + k) * N_ + n];
        const float w = expf((s - rowmax[b * K_ + k]) * inv[b * K_ + k])
                        / rowsum[b * K_ + k];
        if (w > best) { best = w; bi = k; }   // strict > keeps first (jnp tie rule)
    }
    kmaxo[(size_t)b * N_ + n] = bi;
    wselo[(size_t)b * N_ + n] = best;
}

// ---------------------------------------------------------------------------
// build per-(b,k) contiguous index lists (n ascending, deterministic via
// ballot/popc) + segment descriptors. 4 waves per b; light: reads only
// kmax/wsel (32 KB per block).
// ---------------------------------------------------------------------------
__global__ __launch_bounds__(256) void build_lists_kernel(
    const int* __restrict__ kmax, const float* __restrict__ wsel,
    int* __restrict__ listn, float* __restrict__ listw,
    int* __restrict__ cnt, int4* __restrict__ desc, int* __restrict__ segcnt)
{
    const int b = blockIdx.x;
    const int t = threadIdx.x;
    const int wave = t >> 6, lane = t & 63;
    const int* km = kmax + (size_t)b * N_;
    const float* wv = wsel + (size_t)b * N_;
    const unsigned long long lt = (1ull << lane) - 1ull;

    __shared__ int scnt[4][16];

    int c[16];
    #pragma unroll
    for (int k = 0; k < 16; ++k) c[k] = 0;
    const int qbase = wave * 1024;
    for (int base = 0; base < 1024; base += 64) {
        const int kk = km[qbase + base + lane];
        #pragma unroll
        for (int k = 0; k < 16; ++k)
            c[k] += __popcll(__ballot(kk == k));
    }
    if (lane == 0) {
        #pragma unroll
        for (int k = 0; k < 16; ++k) scnt[wave][k] = c[k];
    }
    __syncthreads();

    int tot[16], koff[16];
    int acc = 0;
    #pragma unroll
    for (int k = 0; k < 16; ++k) {
        tot[k] = scnt[0][k] + scnt[1][k] + scnt[2][k] + scnt[3][k];
        koff[k] = acc; acc += tot[k];
    }
    int run[16];
    #pragma unroll
    for (int k = 0; k < 16; ++k) {
        run[k] = koff[k]
               + (wave > 0 ? scnt[0][k] : 0)
               + (wave > 1 ? scnt[1][k] : 0)
               + (wave > 2 ? scnt[2][k] : 0);
    }

    for (int base = 0; base < 1024; base += 64) {
        const int n = qbase + base + lane;
        const int kk = km[n];
        const float w = wv[n];
        #pragma unroll
        for (int k = 0; k < 16; ++k) {
            const unsigned long long m = __ballot(kk == k);
            if (kk == k) {
                const int pos = run[k] + __popcll(m & lt);
                listn[(size_t)b * N_ + pos] = n;
                listw[(size_t)b * N_ + pos] = w;
            }
            run[k] += __popcll(m);
        }
    }

    if (t == 0) {
        int j = 0;
        for (int k = 0; k < 16; ++k) {
            cnt[b * K_ + k] = tot[k];
            for (int s = 0; s < tot[k]; s += SEGROWS_) {
                desc[b * MAXDESC_ + j] =
                    make_int4(k, koff[k] + s, min(SEGROWS_, tot[k] - s),
                              s / SEGROWS_);
                ++j;
            }
        }
        segcnt[b] = j;
    }
}

// ---------------------------------------------------------------------------
// prototype update stage 1, sorted: one block per 128-row segment of a single
// (b,k). 4 FMA per float4, 2-deep software prefetch (covers ~2x HBM latency).
// rg = t/96 walks rows rg, rg+4, ...; rg-partials folded via LDS (fixed order).
// ---------------------------------------------------------------------------
__global__ __launch_bounds__(384) void partial_update_kernel(
    const int* __restrict__ listn, const float* __restrict__ listw,
    const int* __restrict__ segcnt, const int4* __restrict__ desc,
    const float* __restrict__ feats,
    float* __restrict__ partial)       // [B*K, MAXSEG, C]
{
    const int b = blockIdx.y;
    const int j = blockIdx.x;
    if (j >= segcnt[b]) return;
    const int4 dd = desc[b * MAXDESC_ + j];
    const int k = dd.x, start = dd.y, rows = dd.z, seg = dd.w;
    const int t = threadIdx.x;
    const int rg = t / 96, ci = t % 96;

    __shared__ int   sn[SEGROWS_];
    __shared__ float sw[SEGROWS_];
    if (t < SEGROWS_) {
        const int ok = t < rows;
        sn[t] = ok ? listn[(size_t)b * N_ + start + t] : 0;
        sw[t] = ok ? listw[(size_t)b * N_ + start + t] : 0.f;
    }
    __syncthreads();

    const float4* fb = (const float4*)(feats + (size_t)b * N_ * C_);
    float4 acc = make_float4(0.f, 0.f, 0.f, 0.f);
    if (rg < rows) {
        const int last = rows - 1;
        float  w0 = sw[rg];
        float4 f0 = fb[(size_t)sn[rg] * 96 + ci];
        const int i1 = (rg + 4 <= last) ? rg + 4 : last;
        float  w1 = sw[i1];
        float4 f1 = fb[(size_t)sn[i1] * 96 + ci];
        for (int i = rg; i < rows; i += 4) {
            const int i2 = (i + 8 <= last) ? i + 8 : last;   // clamped prefetch
            const float  w2 = sw[i2];
            const float4 f2 = fb[(size_t)sn[i2] * 96 + ci];
            acc.x += w0 * f0.x; acc.y += w0 * f0.y;
            acc.z += w0 * f0.z; acc.w += w0 * f0.w;
            w0 = w1; f0 = f1;
            w1 = w2; f1 = f2;
        }
    }
    __shared__ float4 sacc[3][96];
    if (rg > 0) sacc[rg - 1][ci] = acc;
    __syncthreads();
    if (rg == 0) {
        acc.x += sacc[0][ci].x + sacc[1][ci].x + sacc[2][ci].x;
        acc.y += sacc[0][ci].y + sacc[1][ci].y + sacc[2][ci].y;
        acc.z += sacc[0][ci].z + sacc[1][ci].z + sacc[2][ci].z;
        acc.w += sacc[0][ci].w + sacc[1][ci].w + sacc[2][ci].w;
        ((float4*)partial)[((size_t)(b * K_ + k) * MAXSEG_ + seg) * 96 + ci] = acc;
    }
}

// ---------------------------------------------------------------------------
// stage 2: reduce segment partials -> proto, recompute pnorm; on the last
// iteration also writes the final prototypes to the output buffer.
// ---------------------------------------------------------------------------
__global__ __launch_bounds__(384) void reduce_update_kernel(
    const float* __restrict__ partial, const int* __restrict__ cnt,
    float* __restrict__ proto, float* __restrict__ pnorm,
    float* __restrict__ outp)          // != nullptr on last iteration
{
    const int bk = blockIdx.x;
    const int c = threadIdx.x;
    const int nseg = (cnt[bk] + SEGROWS_ - 1) / SEGROWS_;

    float acc = 0.f;
    for (int s = 0; s < nseg; ++s)
        acc += partial[((size_t)bk * MAXSEG_ + s) * C_ + c];
    proto[(size_t)bk * C_ + c] = acc;
    if (outp) outp[(size_t)bk * C_ + c] = acc;

    float sq = acc * acc;
    #pragma unroll
    for (int m = 1; m <= 32; m <<= 1) sq += __shfl_xor(sq, m, 64);
    __shared__ float red[6];
    const int w = c >> 6, lane = c & 63;
    if (lane == 0) red[w] = sq;
    __syncthreads();
    if (c == 0) {
        float t = red[0] + red[1] + red[2] + red[3] + red[4] + red[5];
        pnorm[bk] = sqrtf(t);
    }
}

// ---------------------------------------------------------------------------
extern "C" void kernel_launch(void* const* d_in, const int* in_sizes, int n_in,
                              void* d_out, int out_size, void* d_ws, size_t ws_size,
                              hipStream_t stream) {
    const float* pin   = (const float*)d_in[0];   // [B,K,C]
    const float* feats = (const float*)d_in[1];   // [B,N,C]
    const float* forg  = (const float*)d_in[2];   // [M,C]
    float* out = (float*)d_out;

    // workspace carve (floats; every block is a multiple of 4 elems = 16B)
    float* ws = (float*)d_ws;
    size_t o = 0;
    float* proto   = ws + o; o += (size_t)B_ * K_ * C_;            // 393216
    float* pnorm   = ws + o; o += 1024;
    float* inv     = ws + o; o += 1024;
    float* rowmax  = ws + o; o += 1024;
    float* rowsum  = ws + o; o += 1024;
    float* fnorm   = ws + o; o += (size_t)B_ * N_;                 // 262144
    float* wsel    = ws + o; o += (size_t)B_ * N_;                 // 262144
    float* listw   = ws + o; o += (size_t)B_ * N_;                 // 262144
    float* sim     = ws + o; o += (size_t)B_ * K_ * N_;            // 4194304
    float* partial = ws + o; o += (size_t)B_ * K_ * MAXSEG_ * C_;  // 12582912
    int*  kmax   = (int*)(ws + o); o += (size_t)B_ * N_;
    int*  listn  = (int*)(ws + o); o += (size_t)B_ * N_;
    int*  cnt    = (int*)(ws + o); o += 1024;
    int*  segcnt = (int*)(ws + o); o += 1024;
    int4* desc   = (int4*)(ws + o); o += (size_t)B_ * MAXDESC_ * 4;

    init_proto_kernel<<<B_ * K_, 384, 0, stream>>>(pin, proto, pnorm);
    // pass 1: compute + store row norms
    sim_kernel<0><<<dim3(N_ / 256, B_), 256, 0, stream>>>(
        proto, pnorm, feats, fnorm, sim, N_, (long long)N_ * C_);

    for (int it = 0; it < 5; ++it) {
        stats_kernel<<<B_ * K_, 256, 0, stream>>>(
            sim, kmax, inv, rowmax, rowsum, it == 0 ? 1 : 0);
        argmax_kernel<<<dim3(N_ / 256, B_), 256, 0, stream>>>(
            sim, rowmax, rowsum, inv, kmax, wsel);
        build_lists_kernel<<<B_, 256, 0, stream>>>(
            kmax, wsel, listn, listw, cnt, desc, segcnt);
        partial_update_kernel<<<dim3(MAXDESC_, B_), 384, 0, stream>>>(
            listn, listw, segcnt, desc, feats, partial);
        reduce_update_kernel<<<B_ * K_, 384, 0, stream>>>(
            partial, cnt, proto, pnorm, it == 4 ? out : nullptr);
        if (it < 4) {
            sim_kernel<1><<<dim3(N_ / 256, B_), 256, 0, stream>>>(
                proto, pnorm, feats, fnorm, sim, N_, (long long)N_ * C_);
        }
    }

    // final: sim against feats_org -> d_out sim region (norms computed in-pass)
    sim_kernel<2><<<dim3(M_ / 256, B_), 256, 0, stream>>>(
        proto, pnorm, forg, fnorm, out + (size_t)B_ * K_ * C_, M_, 0LL);
}

// Round 12
// 1416.892 us; speedup vs baseline: 5.1865x; 1.0133x over previous
//
#include <hip/hip_runtime.h>
#include <hip/hip_bf16.h>

#define B_ 64
#define K_ 16
#define N_ 4096
#define C_ 384
#define M_ 4096
#define EPS_ 1e-8f

#define SEGROWS_ 128
#define MAXSEG_  32          // per (b,k): ceil(4096/128)
#define MAXDESC_ 48          // per b: sum_k ceil(cnt_k/128) < 48

#define TROWS_  16           // rows per LDS stage in sim (24 KB)
#define NSTAGE_ 8            // stages per block (128 rows) — finer grid for
                             // occupancy-quantization balance (3 blocks/CU)

// async global->LDS, 16B per lane, wave-uniform LDS base (+lane*16 in HW)
#define GLDS(gp, lp) __builtin_amdgcn_global_load_lds( \
    (const __attribute__((address_space(1))) unsigned int*)(gp), \
    (__attribute__((address_space(3))) unsigned int*)(lp), 16, 0, 0)

// ---------------------------------------------------------------------------
// init: copy input prototypes into ws and compute their norms
// ---------------------------------------------------------------------------
__global__ __launch_bounds__(384) void init_proto_kernel(
    const float* __restrict__ pin, float* __restrict__ proto,
    float* __restrict__ pnorm)
{
    const int bk = blockIdx.x;
    const int c  = threadIdx.x;            // 384 threads, c == channel
    float v = pin[(size_t)bk * C_ + c];
    proto[(size_t)bk * C_ + c] = v;
    float sq = v * v;
    #pragma unroll
    for (int m = 1; m <= 32; m <<= 1) sq += __shfl_xor(sq, m, 64);
    __shared__ float red[6];
    const int w = c >> 6, lane = c & 63;
    if (lane == 0) red[w] = sq;
    __syncthreads();
    if (c == 0) {
        float t = red[0] + red[1] + red[2] + red[3] + red[4] + red[5];
        pnorm[bk] = sqrtf(t);
    }
}

// ---------------------------------------------------------------------------
// sim: sim[b,k,n] = dot(proto[b,k],feats_row[n]) / max(pnorm*fnorm, EPS)
// LDS-staged pipeline (global_load_lds, linear dest). STRIDED chunk layout:
// lane cc reads 16B-chunks {cc+16i, i=0..5} of the 96-chunk row -> consecutive
// lanes hit consecutive bank-quads (2-way = conflict-free). Proto fragments
// use the same chunk layout so the dot products stay element-aligned.
// NM: 0 = compute row norm + store to fnorm; 1 = load fnorm; 2 = compute only.
// ---------------------------------------------------------------------------
template <int NM>
__global__ __launch_bounds__(256) void sim_kernel(
    const float* __restrict__ proto,   // [B,K,C]
    const float* __restrict__ pnorm,   // [B,K]
    const float* __restrict__ feats,   // rows [nrows, C], per-b stride bstride
    float* __restrict__ fnorm,         // [B,nrows] (store NM=0 / load NM=1)
    float* __restrict__ simout,        // [B,K,nrows]
    int nrows, long long bstride)
{
    const int b    = blockIdx.y;
    const int tile = blockIdx.x;           // 128 rows per block
    const int tid  = threadIdx.x;
    const int wave = tid >> 6;
    const int lane = tid & 63;
    const int kg   = lane & 3;
    const int cc   = lane >> 2;
    const int p    = cc & 1;
    const int q    = (cc >> 1) & 1;

    __shared__ float lbuf[2][TROWS_ * C_];     // 2 x 24 KB

    // writer-lane k mapping and its prototype norm
    const int k_w = (lane & 3) * 4 + 2 * ((lane >> 3) & 1) + ((lane >> 2) & 1);
    const float pn_w = pnorm[b * K_ + (k_w & 15)];

    // prototype fragments in registers: 4 k's x 6 strided 16B chunks
    float4 pr[4][6];
    const float* pb = proto + (size_t)b * K_ * C_;
    #pragma unroll
    for (int j = 0; j < 4; ++j) {
        const float* prow = pb + (size_t)(kg * 4 + j) * C_;
        #pragma unroll
        for (int i = 0; i < 6; ++i)
            pr[j][i] = *(const float4*)(prow + (cc + 16 * i) * 4);
    }

    const float* fb = feats + (size_t)b * bstride;
    const int nbase0 = tile * (TROWS_ * NSTAGE_);

    // stage st -> buffer s: linear 24 KB copy, 6 calls x 4 KB
    const int loff = wave * 256 + lane * 4;    // float offset of this lane's 16B
    #define STAGE_(s, st) do {                                              \
        const float* g_ = fb + (size_t)(nbase0 + (st) * TROWS_) * C_ + loff;\
        float* l_ = &lbuf[s][wave * 256];                                   \
        _Pragma("unroll")                                                   \
        for (int i_ = 0; i_ < 6; ++i_)                                      \
            GLDS(g_ + i_ * 1024, l_ + i_ * 1024);                           \
    } while (0)

    STAGE_(0, 0);
    __syncthreads();

    for (int st = 0; st < NSTAGE_; ++st) {
        if (st + 1 < NSTAGE_) STAGE_((st + 1) & 1, st + 1);

        const float* lb = &lbuf[st & 1][0];
        #pragma unroll
        for (int r = 0; r < 4; ++r) {
            const int row = wave * 4 + r;
            const int n = nbase0 + st * TROWS_ + row;
            const float* frow = lb + row * C_;
            float4 f[6];
            #pragma unroll
            for (int i = 0; i < 6; ++i)
                f[i] = *(const float4*)(frow + (cc + 16 * i) * 4);

            float s0 = 0.f, s1 = 0.f, s2 = 0.f, s3 = 0.f, nsq = 0.f;
            #pragma unroll
            for (int i = 0; i < 6; ++i) {
                if (NM != 1)
                    nsq += f[i].x * f[i].x + f[i].y * f[i].y
                         + f[i].z * f[i].z + f[i].w * f[i].w;
                s0 += f[i].x * pr[0][i].x + f[i].y * pr[0][i].y
                    + f[i].z * pr[0][i].z + f[i].w * pr[0][i].w;
                s1 += f[i].x * pr[1][i].x + f[i].y * pr[1][i].y
                    + f[i].z * pr[1][i].z + f[i].w * pr[1][i].w;
                s2 += f[i].x * pr[2][i].x + f[i].y * pr[2][i].y
                    + f[i].z * pr[2][i].z + f[i].w * pr[2][i].w;
                s3 += f[i].x * pr[3][i].x + f[i].y * pr[3][i].y
                    + f[i].z * pr[3][i].z + f[i].w * pr[3][i].w;
            }
            // fold A: merge {s0,s1} across cc bit0 (lane bit2)
            float sendA = p ? s0 : s1;
            float recvA = __shfl_xor(sendA, 4, 64);
            float a = (p ? s1 : s0) + recvA;
            // fold B: merge {s2,s3}
            float sendB = p ? s2 : s3;
            float recvB = __shfl_xor(sendB, 4, 64);
            float bb = (p ? s3 : s2) + recvB;
            // fold C: merge {a,b} across cc bit1 (lane bit3)
            float sendC = q ? a : bb;
            float recvC = __shfl_xor(sendC, 8, 64);
            float d = (q ? bb : a) + recvC;
            d += __shfl_xor(d, 16, 64);
            d += __shfl_xor(d, 32, 64);

            float fn;
            if (NM == 1) {
                fn = fnorm[(size_t)b * nrows + n];
            } else {
                #pragma unroll
                for (int m = 4; m <= 32; m <<= 1) nsq += __shfl_xor(nsq, m, 64);
                fn = sqrtf(nsq);
                if (NM == 0 && lane == 0) fnorm[(size_t)b * nrows + n] = fn;
            }
            if (lane < 16) {
                const float denom = fmaxf(pn_w * fn, EPS_);
                simout[((size_t)b * K_ + k_w) * (size_t)nrows + n] = d / denom;
            }
        }
        __syncthreads();
    }
    #undef STAGE_
}

// ---------------------------------------------------------------------------
// stats: per (b,k): density->tau->inv (from prev mask), rowmax, rowsum(exp)
// ---------------------------------------------------------------------------
__global__ __launch_bounds__(256) void stats_kernel(
    const float* __restrict__ sim,     // [B,K,N]
    const int* __restrict__ kmaxp,     // [B,N] previous-iteration assignment
    float* __restrict__ inv, float* __restrict__ rowmax,
    float* __restrict__ rowsum, int iter0)
{
    const int bk = blockIdx.x;
    const int b = bk >> 4, k = bk & 15;
    const int t = threadIdx.x;
    const float* row = sim + (size_t)bk * N_;
    const int*   km  = kmaxp + (size_t)b * N_;

    float4 v[4];
    float mx = -3.0e38f, ms = 0.f;
    int mc = 0;
    #pragma unroll
    for (int i = 0; i < 4; ++i) {
        v[i] = ((const float4*)row)[i * 256 + t];
        mx = fmaxf(mx, fmaxf(fmaxf(v[i].x, v[i].y), fmaxf(v[i].z, v[i].w)));
    }
    if (!iter0) {
        #pragma unroll
        for (int i = 0; i < 4; ++i) {
            const int4 kk = ((const int4*)km)[i * 256 + t];
            if (kk.x == k) { ms += v[i].x; mc++; }
            if (kk.y == k) { ms += v[i].y; mc++; }
            if (kk.z == k) { ms += v[i].z; mc++; }
            if (kk.w == k) { ms += v[i].w; mc++; }
        }
    }
    __shared__ float smx[4], sms[4];
    __shared__ int   smc[4];
    #pragma unroll
    for (int m = 1; m <= 32; m <<= 1) {
        mx = fmaxf(mx, __shfl_xor(mx, m, 64));
        ms += __shfl_xor(ms, m, 64);
        mc += __shfl_xor(mc, m, 64);
    }
    const int w = t >> 6, lane = t & 63;
    if (lane == 0) { smx[w] = mx; sms[w] = ms; smc[w] = mc; }
    __syncthreads();
    mx = fmaxf(fmaxf(smx[0], smx[1]), fmaxf(smx[2], smx[3]));
    ms = sms[0] + sms[1] + sms[2] + sms[3];
    mc = smc[0] + smc[1] + smc[2] + smc[3];

    float invv;
    if (iter0) {
        invv = 100.f;                     // 1/(temp*tau0) = 1/(0.1*0.1)
    } else {
        const float d   = (mc >= 1) ? (1.f - ms / (float)mc) : 1.f;
        const float tau = fmaxf(d, 1e-10f);
        invv = 1.f / (0.1f * tau);
    }
    float es = 0.f;
    #pragma unroll
    for (int i = 0; i < 4; ++i) {
        es += expf((v[i].x - mx) * invv) + expf((v[i].y - mx) * invv)
            + expf((v[i].z - mx) * invv) + expf((v[i].w - mx) * invv);
    }
    #pragma unroll
    for (int m = 1; m <= 32; m <<= 1) es += __shfl_xor(es, m, 64);
    __syncthreads();
    if (lane == 0) sms[w] = es;
    __syncthreads();
    if (t == 0) {
        rowmax[bk] = mx;
        rowsum[bk] = sms[0] + sms[1] + sms[2] + sms[3];
        inv[bk]    = invv;
    }
}

// ---------------------------------------------------------------------------
// argmax over k of softmax weight; full-machine grid (16,64). Emits winner
// index + winning weight to global for the (light) build kernel.
// ---------------------------------------------------------------------------
__global__ __launch_bounds__(256) void argmax_kernel(
    const float* __restrict__ sim, const float* __restrict__ rowmax,
    const float* __restrict__ rowsum, const float* __restrict__ inv,
    int* __restrict__ kmaxo, float* __restrict__ wselo)
{
    const int b = blockIdx.y;
    const int n = blockIdx.x * 256 + threadIdx.x;
    float best = -1.f;
    int bi = 0;
    #pragma unroll
    for (int k = 0; k < K_; ++k) {
        const float s = sim[((size_t)b * K_ + k) * N_ + n];
        const float w = expf((s - rowmax[b * K_ + k]) * inv[b * K_ + k])
                        / rowsum[b * K_ + k];
        if (w > best) { best = w; bi = k; }   // strict > keeps first (jnp tie rule)
    }
    kmaxo[(size_t)b * N_ + n] = bi;
    wselo[(size_t)b * N_ + n] = best;
}

// ---------------------------------------------------------------------------
// build per-(b,k) contiguous index lists (n ascending, deterministic via
// ballot/popc) + segment descriptors. 4 waves per b; light: reads only
// kmax/wsel (32 KB per block).
// ---------------------------------------------------------------------------
__global__ __launch_bounds__(256) void build_lists_kernel(
    const int* __restrict__ kmax, const float* __restrict__ wsel,
    int* __restrict__ listn, float* __restrict__ listw,
    int* __restrict__ cnt, int4* __restrict__ desc, int* __restrict__ segcnt)
{
    const int b = blockIdx.x;
    const int t = threadIdx.x;
    const int wave = t >> 6, lane = t & 63;
    const int* km = kmax + (size_t)b * N_;
    const float* wv = wsel + (size_t)b * N_;
    const unsigned long long lt = (1ull << lane) - 1ull;

    __shared__ int scnt[4][16];

    int c[16];
    #pragma unroll
    for (int k = 0; k < 16; ++k) c[k] = 0;
    const int qbase = wave * 1024;
    for (int base = 0; base < 1024; base += 64) {
        const int kk = km[qbase + base + lane];
        #pragma unroll
        for (int k = 0; k < 16; ++k)
            c[k] += __popcll(__ballot(kk == k));
    }
    if (lane == 0) {
        #pragma unroll
        for (int k = 0; k < 16; ++k) scnt[wave][k] = c[k];
    }
    __syncthreads();

    int tot[16], koff[16];
    int acc = 0;
    #pragma unroll
    for (int k = 0; k < 16; ++k) {
        tot[k] = scnt[0][k] + scnt[1][k] + scnt[2][k] + scnt[3][k];
        koff[k] = acc; acc += tot[k];
    }
    int run[16];
    #pragma unroll
    for (int k = 0; k < 16; ++k) {
        run[k] = koff[k]
               + (wave > 0 ? scnt[0][k] : 0)
               + (wave > 1 ? scnt[1][k] : 0)
               + (wave > 2 ? scnt[2][k] : 0);
    }

    for (int base = 0; base < 1024; base += 64) {
        const int n = qbase + base + lane;
        const int kk = km[n];
        const float w = wv[n];
        #pragma unroll
        for (int k = 0; k < 16; ++k) {
            const unsigned long long m = __ballot(kk == k);
            if (kk == k) {
                const int pos = run[k] + __popcll(m & lt);
                listn[(size_t)b * N_ + pos] = n;
                listw[(size_t)b * N_ + pos] = w;
            }
            run[k] += __popcll(m);
        }
    }

    if (t == 0) {
        int j = 0;
        for (int k = 0; k < 16; ++k) {
            cnt[b * K_ + k] = tot[k];
            for (int s = 0; s < tot[k]; s += SEGROWS_) {
                desc[b * MAXDESC_ + j] =
                    make_int4(k, koff[k] + s, min(SEGROWS_, tot[k] - s),
                              s / SEGROWS_);
                ++j;
            }
        }
        segcnt[b] = j;
    }
}

// ---------------------------------------------------------------------------
// prototype update stage 1, sorted: one block per 128-row segment of a single
// (b,k). 4 FMA per float4, 2-deep software prefetch (covers ~2x HBM latency).
// rg = t/96 walks rows rg, rg+4, ...; rg-partials folded via LDS (fixed order).
// ---------------------------------------------------------------------------
__global__ __launch_bounds__(384) void partial_update_kernel(
    const int* __restrict__ listn, const float* __restrict__ listw,
    const int* __restrict__ segcnt, const int4* __restrict__ desc,
    const float* __restrict__ feats,
    float* __restrict__ partial)       // [B*K, MAXSEG, C]
{
    const int b = blockIdx.y;
    const int j = blockIdx.x;
    if (j >= segcnt[b]) return;
    const int4 dd = desc[b * MAXDESC_ + j];
    const int k = dd.x, start = dd.y, rows = dd.z, seg = dd.w;
    const int t = threadIdx.x;
    const int rg = t / 96, ci = t % 96;

    __shared__ int   sn[SEGROWS_];
    __shared__ float sw[SEGROWS_];
    if (t < SEGROWS_) {
        const int ok = t < rows;
        sn[t] = ok ? listn[(size_t)b * N_ + start + t] : 0;
        sw[t] = ok ? listw[(size_t)b * N_ + start + t] : 0.f;
    }
    __syncthreads();

    const float4* fb = (const float4*)(feats + (size_t)b * N_ * C_);
    float4 acc = make_float4(0.f, 0.f, 0.f, 0.f);
    if (rg < rows) {
        const int last = rows - 1;
        float  w0 = sw[rg];
        float4 f0 = fb[(size_t)sn[rg] * 96 + ci];
        const int i1 = (rg + 4 <= last) ? rg + 4 : last;
        float  w1 = sw[i1];
        float4 f1 = fb[(size_t)sn[i1] * 96 + ci];
        for (int i = rg; i < rows; i += 4) {
            const int i2 = (i + 8 <= last) ? i + 8 : last;   // clamped prefetch
            const float  w2 = sw[i2];
            const float4 f2 = fb[(size_t)sn[i2] * 96 + ci];
            acc.x += w0 * f0.x; acc.y += w0 * f0.y;
            acc.z += w0 * f0.z; acc.w += w0 * f0.w;
            w0 = w1; f0 = f1;
            w1 = w2; f1 = f2;
        }
    }
    __shared__ float4 sacc[3][96];
    if (rg > 0) sacc[rg - 1][ci] = acc;
    __syncthreads();
    if (rg == 0) {
        acc.x += sacc[0][ci].x + sacc[1][ci].x + sacc[2][ci].x;
        acc.y += sacc[0][ci].y + sacc[1][ci].y + sacc[2][ci].y;
        acc.z += sacc[0][ci].z + sacc[1][ci].z + sacc[2][ci].z;
        acc.w += sacc[0][ci].w + sacc[1][ci].w + sacc[2][ci].w;
        ((float4*)partial)[((size_t)(b * K_ + k) * MAXSEG_ + seg) * 96 + ci] = acc;
    }
}

// ---------------------------------------------------------------------------
// stage 2: reduce segment partials -> proto, recompute pnorm; on the last
// iteration also writes the final prototypes to the output buffer.
// ---------------------------------------------------------------------------
__global__ __launch_bounds__(384) void reduce_update_kernel(
    const float* __restrict__ partial, const int* __restrict__ cnt,
    float* __restrict__ proto, float* __restrict__ pnorm,
    float* __restrict__ outp)          // != nullptr on last iteration
{
    const int bk = blockIdx.x;
    const int c = threadIdx.x;
    const int nseg = (cnt[bk] + SEGROWS_ - 1) / SEGROWS_;

    float acc = 0.f;
    for (int s = 0; s < nseg; ++s)
        acc += partial[((size_t)bk * MAXSEG_ + s) * C_ + c];
    proto[(size_t)bk * C_ + c] = acc;
    if (outp) outp[(size_t)bk * C_ + c] = acc;

    float sq = acc * acc;
    #pragma unroll
    for (int m = 1; m <= 32; m <<= 1) sq += __shfl_xor(sq, m, 64);
    __shared__ float red[6];
    const int w = c >> 6, lane = c & 63;
    if (lane == 0) red[w] = sq;
    __syncthreads();
    if (c == 0) {
        float t = red[0] + red[1] + red[2] + red[3] + red[4] + red[5];
        pnorm[bk] = sqrtf(t);
    }
}

// ---------------------------------------------------------------------------
extern "C" void kernel_launch(void* const* d_in, const int* in_sizes, int n_in,
                              void* d_out, int out_size, void* d_ws, size_t ws_size,
                              hipStream_t stream) {
    const float* pin   = (const float*)d_in[0];   // [B,K,C]
    const float* feats = (const float*)d_in[1];   // [B,N,C]
    const float* forg  = (const float*)d_in[2];   // [M,C]
    float* out = (float*)d_out;

    // workspace carve (floats; every block is a multiple of 4 elems = 16B)
    float* ws = (float*)d_ws;
    size_t o = 0;
    float* proto   = ws + o; o += (size_t)B_ * K_ * C_;            // 393216
    float* pnorm   = ws + o; o += 1024;
    float* inv     = ws + o; o += 1024;
    float* rowmax  = ws + o; o += 1024;
    float* rowsum  = ws + o; o += 1024;
    float* fnorm   = ws + o; o += (size_t)B_ * N_;                 // 262144
    float* wsel    = ws + o; o += (size_t)B_ * N_;                 // 262144
    float* listw   = ws + o; o += (size_t)B_ * N_;                 // 262144
    float* sim     = ws + o; o += (size_t)B_ * K_ * N_;            // 4194304
    float* partial = ws + o; o += (size_t)B_ * K_ * MAXSEG_ * C_;  // 12582912
    int*  kmax   = (int*)(ws + o); o += (size_t)B_ * N_;
    int*  listn  = (int*)(ws + o); o += (size_t)B_ * N_;
    int*  cnt    = (int*)(ws + o); o += 1024;
    int*  segcnt = (int*)(ws + o); o += 1024;
    int4* desc   = (int4*)(ws + o); o += (size_t)B_ * MAXDESC_ * 4;

    const int ROWS_PER_BLK = TROWS_ * NSTAGE_;    // 128

    init_proto_kernel<<<B_ * K_, 384, 0, stream>>>(pin, proto, pnorm);
    // pass 1: compute + store row norms
    sim_kernel<0><<<dim3(N_ / ROWS_PER_BLK, B_), 256, 0, stream>>>(
        proto, pnorm, feats, fnorm, sim, N_, (long long)N_ * C_);

    for (int it = 0; it < 5; ++it) {
        stats_kernel<<<B_ * K_, 256, 0, stream>>>(
            sim, kmax, inv, rowmax, rowsum, it == 0 ? 1 : 0);
        argmax_kernel<<<dim3(N_ / 256, B_), 256, 0, stream>>>(
            sim, rowmax, rowsum, inv, kmax, wsel);
        build_lists_kernel<<<B_, 256, 0, stream>>>(
            kmax, wsel, listn, listw, cnt, desc, segcnt);
        partial_update_kernel<<<dim3(MAXDESC_, B_), 384, 0, stream>>>(
            listn, listw, segcnt, desc, feats, partial);
        reduce_update_kernel<<<B_ * K_, 384, 0, stream>>>(
            partial, cnt, proto, pnorm, it == 4 ? out : nullptr);
        if (it < 4) {
            sim_kernel<1><<<dim3(N_ / ROWS_PER_BLK, B_), 256, 0, stream>>>(
                proto, pnorm, feats, fnorm, sim, N_, (long long)N_ * C_);
        }
    }

    // final: sim against feats_org -> d_out sim region (norms computed in-pass)
    sim_kernel<2><<<dim3(M_ / ROWS_PER_BLK, B_), 256, 0, stream>>>(
        proto, pnorm, forg, fnorm, out + (size_t)B_ * K_ * C_, M_, 0LL);
}